// Round 11
// baseline (113.026 us; speedup 1.0000x reference)
//
#include <hip/hip_runtime.h>

// MFMA-batched overlapped-chunk HMM forward filter — MEASUREMENT ROUND.
// R16: four store-path theories refuted (R12/R13/R14/R15: {64B,256B}x{alloc,nt}
// = {18.2, 27.7, 19.0, 20.6}us). Kernel pinned ~18us across 4x issue change,
// 2x occupancy change, all store patterns; models predict <=12. The kernel's
// own counters (FETCH/WRITE/VALUBusy/Occupancy) have NEVER been visible --
// always below the top-5 cutoff (fills ~44us). This round repeats the filter
// 3x INSIDE one dispatch (idempotent, same stores each rep) -> dispatch ~55us
// -> top-1 row with counters. Base = R12 (best, simplest). Pre-committed:
//   total ~125 -> floor model ok; ~113 -> kernel ~12us, near roofline.
//   WRITE~150-200MB & FETCH<25MB -> writes drain at 3.6TB/s, no hidden fetch.
//   FETCH>100MB -> hidden read churn is real -> layout fix.
//   VALUBusy>50% -> issue-bound after all.
#define CHUNK_L 16
#define WARMUP_W 16
#define REPS 3

typedef _Float16 h16;
typedef _Float16 h16x4 __attribute__((ext_vector_type(4)));
typedef float f32x4 __attribute__((ext_vector_type(4)));

static __device__ __forceinline__ f32x4 mfma16(h16x4 a, h16x4 b, f32x4 c) {
#if __has_builtin(__builtin_amdgcn_mfma_f32_16x16x16f16)
    return __builtin_amdgcn_mfma_f32_16x16x16f16(a, b, c, 0, 0, 0);
#else
    f32x4 d;
    asm volatile("v_mfma_f32_16x16x16_f16 %0, %1, %2, %3\n\ts_nop 7\n\ts_nop 7"
                 : "=v"(d) : "v"(a), "v"(b), "v"(c));
    return d;
#endif
}

__global__ __launch_bounds__(256, 4) void hmm_filter_kernel(
    const float* __restrict__ y,
    const float* __restrict__ logits,
    const float* __restrict__ mu,
    const float* __restrict__ log_sigma,
    float* __restrict__ out,
    int T, int nchunks)
{
    __shared__ float Plds[256];
    __shared__ float Ba[256];
    __shared__ float Bb[256];

    const int tid = (int)threadIdx.x;
    const int j   = tid & 15;     // column (preamble)
    const int gr  = tid >> 4;     // row (preamble)

    // ---- P = softmax(logits, axis=-1) ----
    float l = logits[tid];
    float m = l;
    #pragma unroll
    for (int s = 1; s < 16; s <<= 1) m = fmaxf(m, __shfl_xor(m, s, 16));
    float e = __expf(l - m);
    float rs = e;
    #pragma unroll
    for (int s = 1; s < 16; s <<= 1) rs += __shfl_xor(rs, s, 16);
    float Pv = e / rs;
    Plds[tid] = Pv;
    Ba[tid]   = Pv;
    __syncthreads();

    // ---- stationary pi: P^(2^10) via renormalized squaring (cold) ----
    float* cur = Ba;
    float* nxt = Bb;
    for (int itq = 0; itq < 10; ++itq) {
        float acc = 0.f;
        #pragma unroll
        for (int k = 0; k < 16; ++k)
            acc += cur[gr * 16 + k] * cur[k * 16 + j];
        float rsum = acc;
        #pragma unroll
        for (int s = 1; s < 16; s <<= 1) rsum += __shfl_xor(rsum, s, 16);
        nxt[tid] = acc / rsum;
        __syncthreads();
        float* tmp = cur; cur = nxt; nxt = tmp;
    }
    // no barriers below this point (early return is safe)

    // ---- lane / wave geometry ----
    const int lane = tid & 63;
    const int col  = lane & 15;          // chunk column  (n)
    const int i0   = (lane >> 4) << 2;   // first of this lane's 4 states
    const int wv   = ((int)blockIdx.x << 2) + (tid >> 6);
    const int cbase = wv << 4;

    // A = P^T fragments, hi/lo f16 split.
    h16x4 Ahi, Alo;
    #pragma unroll
    for (int ee = 0; ee < 4; ++ee) {
        float a = Plds[(i0 + ee) * 16 + col];
        h16 hi = (h16)a;
        Ahi[ee] = hi;
        Alo[ee] = (h16)(a - (float)hi);
    }

    // pi values for this lane (rep-loop re-inits carried state from these)
    f32x4 pi4;
    #pragma unroll
    for (int ee = 0; ee < 4; ++ee) pi4[ee] = cur[i0 + ee];

    // emission constants for this lane's 4 states
    float isv[4], nmv[4], lcv[4];
    #pragma unroll
    for (int ee = 0; ee < 4; ++ee) {
        int st = i0 + ee;
        float is = __expf(-log_sigma[st]);
        isv[ee] = is;
        nmv[ee] = -mu[st] * is;
        lcv[ee] = __log2f(0.3989422804014327f * is);
    }
    const float K2 = -0.7213475204444817f;   // -0.5*log2(e)

    if (cbase >= nchunks) return;

    const int chunk = cbase + col;
    const bool live = chunk < nchunks;       // ghost chunks: no stores
    const bool isC0 = (chunk == 0);          // warm with g==1 (pi stationary)
    const int Tm4 = T - 4;
    const int TN  = T << 4;

    auto yld = [&](int t) -> float4 {
        int tc = t < 0 ? 0 : (t > Tm4 ? Tm4 : t);
        return *(const float4*)(y + tc);
    };

#define FSTEP(YT, WARM, DOST, UTP, UNP, FDST)  do {                       \
    f32x4 D = {0.f, 0.f, 0.f, 0.f};                                       \
    D = mfma16(Ahi, bhi, D);                                              \
    D = mfma16(Alo, bhi, D);                                              \
    D = mfma16(Ahi, blo, D);                                              \
    f32x4 eg;                                                             \
    _Pragma("unroll")                                                     \
    for (int ee = 0; ee < 4; ++ee) {                                      \
        float z  = fmaf((YT), isv[ee], nmv[ee]);                          \
        float gg = __builtin_amdgcn_exp2f(fmaf(z * z, K2, lcv[ee]));      \
        if (WARM) gg = isC0 ? 1.0f : gg;                                  \
        eg[ee] = gg * r1;                                                 \
    }                                                                     \
    f32x4 pg = D * eg;                                                    \
    float sv = (pg.x + pg.y) + (pg.z + pg.w);                             \
    sv += __shfl_xor(sv, 16);                                             \
    sv += __shfl_xor(sv, 32);                                             \
    float rv = __builtin_amdgcn_rcpf(sv);                                 \
    if ((DOST) && live) {                                                 \
        f32x4 ut = D * r1;                                                \
        f32x4 un = pg * rv;                                               \
        *(f32x4*)(UTP) = ut;                                              \
        *(f32x4*)(UNP) = un;                                              \
    }                                                                     \
    if (DOST) { FDST = sv; }                                              \
    _Pragma("unroll")                                                     \
    for (int ee = 0; ee < 4; ++ee) {                                      \
        h16 hh = (h16)pg[ee];                                             \
        bhi[ee] = hh;                                                     \
        blo[ee] = (h16)(pg[ee] - (float)hh);                              \
    }                                                                     \
    r1 = rv;                                                              \
} while (0)

    // ---- REPS identical passes (idempotent stores; measurement x3) ----
    #pragma unroll 1
    for (int rep = 0; rep < REPS; ++rep) {
        h16x4 bhi, blo;
        #pragma unroll
        for (int ee = 0; ee < 4; ++ee) {
            h16 hi = (h16)pi4[ee];
            bhi[ee] = hi;
            blo[ee] = (h16)(pi4[ee] - (float)hi);
        }
        float r1 = 1.0f;
        int tb = chunk * CHUNK_L - WARMUP_W;

        float4 c4 = yld(tb);
        float4 n1 = yld(tb + 4);

        // warm-up: 16 steps, no stores
        float fdummy;
        #pragma unroll 1
        for (int b = 0; b < WARMUP_W / 4; ++b) {
            float4 nn = yld(tb + 8);
            FSTEP(c4.x, true, false, out, out, fdummy);
            FSTEP(c4.y, true, false, out, out, fdummy);
            FSTEP(c4.z, true, false, out, out, fdummy);
            FSTEP(c4.w, true, false, out, out, fdummy);
            c4 = n1; n1 = nn; tb += 4;
        }
        (void)fdummy;

        // main: CHUNK_L steps with stores
        float* pU = out + ((chunk * CHUNK_L) << 4) + i0;   // ut  [t][state]
        float* pN = pU + TN;                               // u_norm
        float* pF = out + 2 * TN + chunk * CHUNK_L;        // ft (lanes<16)
        f32x4 f4;

        #pragma unroll 1
        for (int b = 0; b < CHUNK_L / 4; ++b) {
            float4 nn = yld(tb + 8);
            FSTEP(c4.x, false, true, pU,      pN,      f4.x);
            FSTEP(c4.y, false, true, pU + 16, pN + 16, f4.y);
            FSTEP(c4.z, false, true, pU + 32, pN + 32, f4.z);
            FSTEP(c4.w, false, true, pU + 48, pN + 48, f4.w);
            if (lane < 16 && live) *(f32x4*)(pF) = f4;
            pU += 64; pN += 64; pF += 4;
            c4 = n1; n1 = nn; tb += 4;
        }
    }
#undef FSTEP
}

extern "C" void kernel_launch(void* const* d_in, const int* in_sizes, int n_in,
                              void* d_out, int out_size, void* d_ws, size_t ws_size,
                              hipStream_t stream) {
    const float* y      = (const float*)d_in[0];
    const float* logits = (const float*)d_in[1];
    const float* mu     = (const float*)d_in[2];
    const float* ls     = (const float*)d_in[3];
    float* out = (float*)d_out;
    const int T = in_sizes[0];                 // 500000 = 16 * 31250 (exact)

    const int nchunks = (T + CHUNK_L - 1) / CHUNK_L;
    const int nwaves  = (nchunks + 15) / 16;
    const int blocks  = (nwaves + 3) / 4;
    hmm_filter_kernel<<<blocks, 256, 0, stream>>>(y, logits, mu, ls, out,
                                                  T, nchunks);
}

// Round 13
// 89.504 us; speedup vs baseline: 1.2628x; 1.2628x over previous
//
#include <hip/hip_runtime.h>

// MFMA-batched overlapped-chunk HMM forward filter — FINAL (R12 restored).
// One wave = 16 chunks via v_mfma_f32_16x16x16_f16; D=A@B, A=P^T const,
// B=p~[state][chunk]; B/D (lane,reg) maps identical -> D feeds next B with
// zero cross-lane movement. Split-f16 (Markidis) 3-MFMA chain, 1-step-lag
// normalization (carried scale = f_t, f16-safe). CHUNK_L=16, ~1.9 w/SIMD.
//
// Evidence trail (R16 counters, kernel row finally visible):
//   FETCH ~1.6MB (no hidden reads), WRITE = 66MB/rep (mandatory output),
//   VALUBusy 35%, MfmaUtil 6.7%, bank conflicts ~0.
//   Marginal warm rep = (113.0-89.0)/2 = 12.0us = 66MB @ 5.5 TB/s = 92% of
//   the fill-demonstrated 6.0 TB/s pure-write ceiling -> at write roofline.
//   Single-launch cost exceeds warm rate only because rep overlaps the
//   harness poison-fill drain (388MB total graph writes share one ~6TB/s
//   HBM path ~= 65us + fringe ~= 89us observed). Explains why all five
//   store-path variants (R11-R15) were invariant. No kernel-side lever left.
// (This round: identical resubmission — prior bench died to container
//  acquire failure, no verdict. Same infra error as R1/R4.)
#define CHUNK_L 16
#define WARMUP_W 16

typedef _Float16 h16;
typedef _Float16 h16x4 __attribute__((ext_vector_type(4)));
typedef float f32x4 __attribute__((ext_vector_type(4)));

static __device__ __forceinline__ f32x4 mfma16(h16x4 a, h16x4 b, f32x4 c) {
#if __has_builtin(__builtin_amdgcn_mfma_f32_16x16x16f16)
    return __builtin_amdgcn_mfma_f32_16x16x16f16(a, b, c, 0, 0, 0);
#else
    f32x4 d;
    asm volatile("v_mfma_f32_16x16x16_f16 %0, %1, %2, %3\n\ts_nop 7\n\ts_nop 7"
                 : "=v"(d) : "v"(a), "v"(b), "v"(c));
    return d;
#endif
}

__global__ __launch_bounds__(256, 4) void hmm_filter_kernel(
    const float* __restrict__ y,
    const float* __restrict__ logits,
    const float* __restrict__ mu,
    const float* __restrict__ log_sigma,
    float* __restrict__ out,
    int T, int nchunks)
{
    __shared__ float Plds[256];
    __shared__ float Ba[256];
    __shared__ float Bb[256];

    const int tid = (int)threadIdx.x;
    const int j   = tid & 15;     // column (preamble)
    const int gr  = tid >> 4;     // row (preamble)

    // ---- P = softmax(logits, axis=-1) ----
    float l = logits[tid];
    float m = l;
    #pragma unroll
    for (int s = 1; s < 16; s <<= 1) m = fmaxf(m, __shfl_xor(m, s, 16));
    float e = __expf(l - m);
    float rs = e;
    #pragma unroll
    for (int s = 1; s < 16; s <<= 1) rs += __shfl_xor(rs, s, 16);
    float Pv = e / rs;
    Plds[tid] = Pv;
    Ba[tid]   = Pv;
    __syncthreads();

    // ---- stationary pi: P^(2^10) via renormalized squaring (cold) ----
    float* cur = Ba;
    float* nxt = Bb;
    for (int itq = 0; itq < 10; ++itq) {
        float acc = 0.f;
        #pragma unroll
        for (int k = 0; k < 16; ++k)
            acc += cur[gr * 16 + k] * cur[k * 16 + j];
        float rsum = acc;
        #pragma unroll
        for (int s = 1; s < 16; s <<= 1) rsum += __shfl_xor(rsum, s, 16);
        nxt[tid] = acc / rsum;
        __syncthreads();
        float* tmp = cur; cur = nxt; nxt = tmp;
    }
    // no barriers below this point (early return is safe)

    // ---- lane / wave geometry ----
    const int lane = tid & 63;
    const int col  = lane & 15;          // chunk column  (n)
    const int i0   = (lane >> 4) << 2;   // first of this lane's 4 states
    const int wv   = ((int)blockIdx.x << 2) + (tid >> 6);
    const int cbase = wv << 4;

    // A = P^T fragments, hi/lo f16 split.  A[m][k]: m=lane%16, k=i0+ee.
    // A[m][k] = P[k][m] = Plds[(i0+ee)*16 + col].
    h16x4 Ahi, Alo;
    #pragma unroll
    for (int ee = 0; ee < 4; ++ee) {
        float a = Plds[(i0 + ee) * 16 + col];
        h16 hi = (h16)a;
        Ahi[ee] = hi;
        Alo[ee] = (h16)(a - (float)hi);
    }

    // initial p~ = pi  (B[k][n]: k=i0+ee, same for every chunk column)
    h16x4 bhi, blo;
    #pragma unroll
    for (int ee = 0; ee < 4; ++ee) {
        float pv = cur[i0 + ee];
        h16 hi = (h16)pv;
        bhi[ee] = hi;
        blo[ee] = (h16)(pv - (float)hi);
    }

    // emission constants for this lane's 4 states
    float isv[4], nmv[4], lcv[4];
    #pragma unroll
    for (int ee = 0; ee < 4; ++ee) {
        int st = i0 + ee;
        float is = __expf(-log_sigma[st]);
        isv[ee] = is;
        nmv[ee] = -mu[st] * is;
        lcv[ee] = __log2f(0.3989422804014327f * is);
    }
    const float K2 = -0.7213475204444817f;   // -0.5*log2(e)

    if (cbase >= nchunks) return;

    const int chunk = cbase + col;
    const bool live = chunk < nchunks;       // ghost chunks: no stores
    const bool isC0 = (chunk == 0);          // warm with g==1 (pi stationary)
    const int Tm4 = T - 4;
    const int TN  = T << 4;

    int tb = chunk * CHUNK_L - WARMUP_W;     // t of current y 4-block

    auto yld = [&](int t) -> float4 {
        int tc = t < 0 ? 0 : (t > Tm4 ? Tm4 : t);
        return *(const float4*)(y + tc);
    };

    float4 c4 = yld(tb);
    float4 n1 = yld(tb + 4);

    float r1 = 1.0f;   // rcp(rowsum of previous step) = 1/c_{t-1}

// One filter step. Chain: 3 MFMA -> *eg -> f16 split. rowsum/rcp, outputs
// hang off the chain. alpha = r1 (1-step lag) keeps carried scale = f_t.
#define FSTEP(YT, WARM, DOST, UTP, UNP, FDST)  do {                       \
    f32x4 D = {0.f, 0.f, 0.f, 0.f};                                       \
    D = mfma16(Ahi, bhi, D);                                              \
    D = mfma16(Alo, bhi, D);                                              \
    D = mfma16(Ahi, blo, D);                                              \
    f32x4 eg;                                                             \
    _Pragma("unroll")                                                     \
    for (int ee = 0; ee < 4; ++ee) {                                      \
        float z  = fmaf((YT), isv[ee], nmv[ee]);                          \
        float gg = __builtin_amdgcn_exp2f(fmaf(z * z, K2, lcv[ee]));      \
        if (WARM) gg = isC0 ? 1.0f : gg;                                  \
        eg[ee] = gg * r1;                                                 \
    }                                                                     \
    f32x4 pg = D * eg;                                                    \
    float sv = (pg.x + pg.y) + (pg.z + pg.w);                             \
    sv += __shfl_xor(sv, 16);                                             \
    sv += __shfl_xor(sv, 32);                                             \
    float rv = __builtin_amdgcn_rcpf(sv);                                 \
    if ((DOST) && live) {                                                 \
        f32x4 ut = D * r1;                                                \
        f32x4 un = pg * rv;                                               \
        *(f32x4*)(UTP) = ut;                                              \
        *(f32x4*)(UNP) = un;                                              \
    }                                                                     \
    if (DOST) { FDST = sv; }                                              \
    _Pragma("unroll")                                                     \
    for (int ee = 0; ee < 4; ++ee) {                                      \
        h16 hh = (h16)pg[ee];                                             \
        bhi[ee] = hh;                                                     \
        blo[ee] = (h16)(pg[ee] - (float)hh);                              \
    }                                                                     \
    r1 = rv;                                                              \
} while (0)

    // ---- warm-up: 16 steps, no stores ----
    float fdummy;
    #pragma unroll 1
    for (int b = 0; b < WARMUP_W / 4; ++b) {
        float4 nn = yld(tb + 8);
        FSTEP(c4.x, true, false, out, out, fdummy);
        FSTEP(c4.y, true, false, out, out, fdummy);
        FSTEP(c4.z, true, false, out, out, fdummy);
        FSTEP(c4.w, true, false, out, out, fdummy);
        c4 = n1; n1 = nn; tb += 4;
    }
    (void)fdummy;

    // ---- main: CHUNK_L steps with stores ----
    float* pU = out + ((chunk * CHUNK_L) << 4) + i0;   // ut  [t][state]
    float* pN = pU + TN;                               // u_norm
    float* pF = out + 2 * TN + chunk * CHUNK_L;        // ft (lanes<16)
    f32x4 f4;

    #pragma unroll 1
    for (int b = 0; b < CHUNK_L / 4; ++b) {
        float4 nn = yld(tb + 8);
        FSTEP(c4.x, false, true, pU,      pN,      f4.x);
        FSTEP(c4.y, false, true, pU + 16, pN + 16, f4.y);
        FSTEP(c4.z, false, true, pU + 32, pN + 32, f4.z);
        FSTEP(c4.w, false, true, pU + 48, pN + 48, f4.w);
        if (lane < 16 && live) *(f32x4*)(pF) = f4;
        pU += 64; pN += 64; pF += 4;
        c4 = n1; n1 = nn; tb += 4;
    }
#undef FSTEP
}

extern "C" void kernel_launch(void* const* d_in, const int* in_sizes, int n_in,
                              void* d_out, int out_size, void* d_ws, size_t ws_size,
                              hipStream_t stream) {
    const float* y      = (const float*)d_in[0];
    const float* logits = (const float*)d_in[1];
    const float* mu     = (const float*)d_in[2];
    const float* ls     = (const float*)d_in[3];
    float* out = (float*)d_out;
    const int T = in_sizes[0];                 // 500000 = 16 * 31250 (exact)

    const int nchunks = (T + CHUNK_L - 1) / CHUNK_L;
    const int nwaves  = (nchunks + 15) / 16;
    const int blocks  = (nwaves + 3) / 4;
    hmm_filter_kernel<<<blocks, 256, 0, stream>>>(y, logits, mu, ls, out,
                                                  T, nchunks);
}